// Round 8
// baseline (132.928 us; speedup 1.0000x reference)
//
#include <hip/hip_runtime.h>
#include <stdint.h>

#define NB 32
#define NM 6300
#define NC 80
#define NTOP 1000
#define NPAD 1024
#define NCAND 2048
#define NBINS 4096

static constexpr float IMGSZ   = 320.0f;
static constexpr float CONF_TH = 0.05f;
static constexpr float NMS_TH  = 0.6f;
static constexpr float EPSF    = 1e-10f;

// ---- workspace layout (bytes) ----
static constexpr size_t OFF_SCORES = 0;                                    // f32 [NB*NM]
static constexpr size_t OFF_LABELS = OFF_SCORES + (size_t)NB * NM * 4;     // i32 [NB*NM]
static constexpr size_t OFF_NBOX   = OFF_LABELS + (size_t)NB * NM * 4;     // f32 [NB*NPAD*4]
static constexpr size_t OFF_NLAB   = OFF_NBOX   + (size_t)NB * NPAD * 16;  // i32 [NB*NPAD]
static constexpr size_t OFF_SUP    = ((OFF_NLAB + (size_t)NB * NPAD * 4) + 1023) & ~(size_t)1023; // u64 [NB*16*16*64]

// ---------------------------------------------------------------------------
// K1: per-anchor score = sigmoid(conf) * max(softmax(cls)), label = argmax.
// NOTE: numerics (lane->class map, sum order) frozen — rank ties depend on it.
// ---------------------------------------------------------------------------
__global__ __launch_bounds__(256) void k_score(const float* __restrict__ conf,
                                               const float* __restrict__ cls,
                                               float* __restrict__ scores,
                                               int* __restrict__ labels) {
#pragma clang fp contract(off)
    int t = blockIdx.x * blockDim.x + threadIdx.x;
    int a = t >> 4;          // anchor index in [0, NB*NM)
    int l = t & 15;
    if (a >= NB * NM) return;
    const float* row = cls + (size_t)a * NC;

    float v[5];
#pragma unroll
    for (int k = 0; k < 5; ++k) v[k] = row[l + 16 * k];

    float bv = v[0];
    int bi = l;
#pragma unroll
    for (int k = 1; k < 5; ++k) {
        int c = l + 16 * k;
        if (v[k] > bv) { bv = v[k]; bi = c; }
    }
#pragma unroll
    for (int m = 1; m < 16; m <<= 1) {
        float ov = __shfl_xor(bv, m, 16);
        int   oi = __shfl_xor(bi, m, 16);
        if (ov > bv || (ov == bv && oi < bi)) { bv = ov; bi = oi; }
    }
    float s = 0.0f;
#pragma unroll
    for (int k = 0; k < 5; ++k) s += expf(v[k] - bv);
#pragma unroll
    for (int m = 1; m < 16; m <<= 1) s += __shfl_xor(s, m, 16);

    if (l == 0) {
        float cf  = conf[a];
        float sig = 1.0f / (1.0f + expf(-cf));
        float inv = 1.0f / s;
        scores[a] = sig * inv;
        labels[a] = bi;
    }
}

// ---------------------------------------------------------------------------
// K2: sort-free top-k via direct rank computation + fused decode.
// One block (1024 thr) per batch, ~5 barriers, no block-wide sort.
//   rank(key) = suffix_excl(bin)                  [4096-bin 2-stage scan]
//             + #{same-bin keys greater}          [LDS atomicExch chains]
//   out[rank] = decode(candidate)                 [perfect scatter]
// Keys (score_bits<<32 | ~idx) unique -> exact lax.top_k order.
// ---------------------------------------------------------------------------
__global__ __launch_bounds__(1024) void k_topk(const float* __restrict__ scores,
                                               const int* __restrict__ labels,
                                               const float* __restrict__ reg,
                                               const float* __restrict__ anchors,
                                               const float* __restrict__ stridemap,
                                               float* __restrict__ out_scores,
                                               float* __restrict__ out_labels,
                                               float* __restrict__ out_boxes,
                                               float* __restrict__ nbox,
                                               int* __restrict__ nlab) {
#pragma clang fp contract(off)
    __shared__ uint32_t hist[NBINS];      // 16 KiB
    __shared__ uint32_t suf[NBINS];       // 16 KiB  (exclusive suffix counts)
    __shared__ int      binHead[NBINS];   // 16 KiB  (candidate chain heads)
    __shared__ uint16_t nxt[NM];          // 12.3 KiB (chain next, 0xFFFF = end)
    __shared__ uint16_t candList[NCAND];  // 4 KiB
    __shared__ uint32_t csuf[64];
    __shared__ int sT, scnt;

    int b = blockIdx.x, tid = threadIdx.x;
    const float* sb = scores + (size_t)b * NM;

    for (int i = tid; i < NBINS; i += 1024) { hist[i] = 0; binHead[i] = -1; }
    if (tid == 0) scnt = 0;
    __syncthreads();

    // pass 1: histogram of top-12 float bits (scores > 0 -> bit-monotone)
    for (int i = tid; i < NM; i += 1024)
        atomicAdd(&hist[__float_as_uint(sb[i]) >> 20], 1u);
    __syncthreads();

    // stage A: chunk sums (64 chunks of 64) + exclusive suffix across chunks
    if (tid < 64) {
        uint32_t cs = 0;
        for (int k = 0; k < 64; ++k) cs += hist[tid * 64 + k];
        uint32_t s = cs;
        for (int off = 1; off < 64; off <<= 1) {
            uint32_t o = __shfl_down(s, off);
            if (tid + off < 64) s += o;
        }
        csuf[tid] = s - cs;               // sum of chunks strictly above
    }
    __syncthreads();

    // stage B: full exclusive suffix for all 4096 bins + threshold bin T
    int ln = tid & 63, wv = tid >> 6;
    for (int c = wv; c < 64; c += 16) {
        uint32_t h = hist[c * 64 + ln];
        uint32_t s = h;
        for (int off = 1; off < 64; off <<= 1) {
            uint32_t o = __shfl_down(s, off);
            if (ln + off < 64) s += o;
        }
        uint32_t sufv = csuf[c] + (s - h);   // keys in bins strictly greater
        suf[c * 64 + ln] = sufv;
        if (sufv < (uint32_t)NTOP && sufv + h >= (uint32_t)NTOP)
            sT = c * 64 + ln;                 // unique crossing bin (h > 0)
    }
    __syncthreads();
    uint32_t T = (uint32_t)sT;

    // pass 2a: build same-bin chains + candidate list (order irrelevant)
    for (int i = tid; i < NM; i += 1024) {
        uint32_t bin = __float_as_uint(sb[i]) >> 20;
        if (bin >= T) {
            int prev = atomicExch(&binHead[bin], i);
            nxt[i] = (uint16_t)(prev < 0 ? 0xFFFFu : (uint32_t)prev);
            int p = atomicAdd(&scnt, 1);
            if (p < NCAND) candList[p] = (uint16_t)i;
        }
    }
    __syncthreads();

    // pass 2b: exact rank + fused decode scatter
    int C = scnt; if (C > NCAND) C = NCAND;
    for (int c = tid; c < C; c += 1024) {
        int i = candList[c];
        uint32_t bits = __float_as_uint(sb[i]);
        uint32_t bin  = bits >> 20;
        uint32_t rank = suf[bin];
        for (int m = binHead[bin]; m >= 0; ) {
            if (m != i) {
                uint32_t mb = __float_as_uint(sb[m]);
                if (mb > bits || (mb == bits && m < i)) ++rank;   // key_m > key_i
            }
            uint16_t nx = nxt[m];
            m = (nx == 0xFFFFu) ? -1 : (int)nx;
        }
        if (rank < (uint32_t)NTOP) {
            out_scores[b * NTOP + rank] = __uint_as_float(bits);
            int lab = labels[(size_t)b * NM + i];
            out_labels[b * NTOP + rank] = (float)lab;

            const float* rg = reg + ((size_t)b * NM + i) * 4;
            float rx = rg[0], ry = rg[1], rw = rg[2], rh = rg[3];
            const float* an = anchors + (size_t)i * 4;
            float ax = an[0], ay = an[1], aw = an[2], ah = an[3];
            float st = stridemap[i];

            float sx = 1.0f / (1.0f + expf(-rx));
            float sy = 1.0f / (1.0f + expf(-ry));
            float cx = ax + sx * st;
            float cy = ay + sy * st;
            float w  = aw * expf(rw);
            float h  = ah * expf(rh);
            float x1 = cx - 0.5f * w, y1 = cy - 0.5f * h;
            float x2 = cx + 0.5f * w, y2 = cy + 0.5f * h;

            float nx1 = fminf(fmaxf(x1 / IMGSZ, 0.0f), 1.0f);
            float ny1 = fminf(fmaxf(y1 / IMGSZ, 0.0f), 1.0f);
            float nx2 = fminf(fmaxf(x2 / IMGSZ, 0.0f), 1.0f);
            float ny2 = fminf(fmaxf(y2 / IMGSZ, 0.0f), 1.0f);

            float4 bx = make_float4(nx1, ny1, nx2, ny2);
            ((float4*)out_boxes)[b * NTOP + rank] = bx;
            ((float4*)nbox)[b * NPAD + rank]      = bx;
            nlab[b * NPAD + rank] = lab;
        }
    }
}

// ---------------------------------------------------------------------------
// K4: suppression bit-matrix. 256-thr block per 64x64 tile; 4 waves, each
// wave owns 16 columns. lane = row i (box in regs); column box broadcast
// via __shfl (wave-uniform index); column word = __ballot(pred).
// sup[b][tj][ti][j0]: bit ii set iff i=ti*64+ii suppresses j=tj*64+j0.
// ---------------------------------------------------------------------------
__global__ __launch_bounds__(256) void k_supmat(const float* __restrict__ nbox,
                                                const int* __restrict__ nlab,
                                                uint64_t* __restrict__ sup) {
#pragma clang fp contract(off)
    int b = blockIdx.y;
    int t = blockIdx.x;                 // 0..135 triangular pair index
    int tj = (int)((sqrtf(8.0f * (float)t + 1.0f) - 1.0f) * 0.5f);
    while ((tj + 1) * (tj + 2) / 2 <= t) ++tj;
    while (tj * (tj + 1) / 2 > t) --tj;
    int ti = t - tj * (tj + 1) / 2;

    int lane = threadIdx.x & 63;
    int w    = threadIdx.x >> 6;        // column quarter 0..3

    int i = ti * 64 + lane;             // row owned by this lane
    int j = tj * 64 + lane;             // column data this lane republishes

    float4 bi = ((const float4*)nbox)[b * NPAD + i];
    float  ai = (bi.z - bi.x) * (bi.w - bi.y);
    int    li = nlab[b * NPAD + i];
    float4 bj = ((const float4*)nbox)[b * NPAD + j];
    int    lj = nlab[b * NPAD + j];
    bool   iv = (i < NTOP);

    uint64_t mybits = 0;
#pragma unroll
    for (int u = 0; u < 16; ++u) {
        int jj = (w << 4) | u;          // wave-uniform column index
        float bjx = __shfl(bj.x, jj);
        float bjy = __shfl(bj.y, jj);
        float bjz = __shfl(bj.z, jj);
        float bjw = __shfl(bj.w, jj);
        int   ljv = __shfl(lj, jj);
        float ajv = (bjz - bjx) * (bjw - bjy);
        int   jg  = tj * 64 + jj;
        float xx1 = fmaxf(bi.x, bjx);
        float yy1 = fmaxf(bi.y, bjy);
        float xx2 = fminf(bi.z, bjz);
        float yy2 = fminf(bi.w, bjw);
        float inter = fmaxf(EPSF, xx2 - xx1) * fmaxf(EPSF, yy2 - yy1);
        float uni   = fmaxf(ai + ajv - inter, EPSF);
        float iou   = inter / uni;
        bool pred = (i < jg) && iv && (jg < NTOP) && (li == ljv) && (iou > NMS_TH);
        uint64_t bal = __ballot(pred);
        if (lane == jj) mybits = bal;
    }
    if ((lane >> 4) == w)
        sup[(((size_t)b * 16 + tj) * 16 + ti) * 64 + lane] = mybits;
}

// ---------------------------------------------------------------------------
// K5: greedy NMS scan, 16 waves per batch (wave w = column-block tj=w).
// ---------------------------------------------------------------------------
__global__ __launch_bounds__(1024) void k_nms(const float* __restrict__ out_scores,
                                              const uint64_t* __restrict__ sup,
                                              float* __restrict__ out_keep) {
    __shared__ uint64_t Kw[16];
    int b    = blockIdx.x;
    int w    = threadIdx.x >> 6;    // wave id = tj block
    int lane = threadIdx.x & 63;
    const uint64_t* supb = sup + (size_t)b * 16 * 16 * 64;

    uint64_t wrow[16];
#pragma unroll
    for (int ti = 0; ti < 16; ++ti)
        wrow[ti] = (ti <= w) ? supb[((size_t)w * 16 + ti) * 64 + lane] : 0ULL;

    int pos = w * 64 + lane;
    bool k0 = (pos < NTOP) && (out_scores[b * NTOP + pos] >= CONF_TH);

    uint64_t ext = 0;
#pragma unroll
    for (int s = 0; s < 16; ++s) {
        if (w == s) {
            bool cand = k0 && (ext == 0ULL);
            uint64_t wself = wrow[s];
            uint64_t alive = __ballot(cand);
            for (int it = 0; it < 64; ++it) {
                bool dead = (wself & alive) != 0ULL;
                uint64_t na = __ballot(cand && !dead);
                if (na == alive) break;
                alive = na;
            }
            if (lane == 0) Kw[s] = alive;
            if (pos < NTOP)
                out_keep[b * NTOP + pos] = ((alive >> lane) & 1ULL) ? 1.0f : 0.0f;
        }
        __syncthreads();
        if (w > s) ext |= wrow[s] & Kw[s];
    }
}

// ---------------------------------------------------------------------------
extern "C" void kernel_launch(void* const* d_in, const int* in_sizes, int n_in,
                              void* d_out, int out_size, void* d_ws, size_t ws_size,
                              hipStream_t stream) {
    const float* conf = (const float*)d_in[0];
    const float* cls  = (const float*)d_in[1];
    const float* reg  = (const float*)d_in[2];
    const float* anch = (const float*)d_in[3];
    const float* strm = (const float*)d_in[4];

    float* out        = (float*)d_out;
    float* out_scores = out;
    float* out_labels = out + NB * NTOP;
    float* out_boxes  = out + 2 * NB * NTOP;
    float* out_keep   = out + 2 * NB * NTOP + NB * NTOP * 4;

    char* ws = (char*)d_ws;
    float*    scores = (float*)(ws + OFF_SCORES);
    int*      labels = (int*)(ws + OFF_LABELS);
    float*    nbox   = (float*)(ws + OFF_NBOX);
    int*      nlab   = (int*)(ws + OFF_NLAB);
    uint64_t* sup    = (uint64_t*)(ws + OFF_SUP);

    k_score<<<(NB * NM * 16) / 256, 256, 0, stream>>>(conf, cls, scores, labels);
    k_topk<<<NB, 1024, 0, stream>>>(scores, labels, reg, anch, strm,
                                    out_scores, out_labels, out_boxes, nbox, nlab);
    k_supmat<<<dim3(136, NB), 256, 0, stream>>>(nbox, nlab, sup);
    k_nms<<<NB, 1024, 0, stream>>>(out_scores, sup, out_keep);
}

// Round 9
// 80.334 us; speedup vs baseline: 1.6547x; 1.6547x over previous
//
#include <hip/hip_runtime.h>
#include <stdint.h>

#define NB 32
#define NM 6300
#define NC 80
#define NTOP 1000
#define NPAD 1024
#define NCAND 2048
#define NBINS 4096

static constexpr float IMGSZ   = 320.0f;
static constexpr float CONF_TH = 0.05f;
static constexpr float NMS_TH  = 0.6f;
static constexpr float EPSF    = 1e-10f;

// ---- workspace layout (bytes) ----
static constexpr size_t OFF_SCORES = 0;                                    // f32 [NB*NM]
static constexpr size_t OFF_LABELS = OFF_SCORES + (size_t)NB * NM * 4;     // i32 [NB*NM]
static constexpr size_t OFF_TIDX   = OFF_LABELS + (size_t)NB * NM * 4;     // i32 [NB*NPAD]
static constexpr size_t OFF_NBOX   = OFF_TIDX   + (size_t)NB * NPAD * 4;   // f32 [NB*NPAD*4]
static constexpr size_t OFF_NLAB   = OFF_NBOX   + (size_t)NB * NPAD * 16;  // i32 [NB*NPAD]
static constexpr size_t OFF_SUP    = ((OFF_NLAB + (size_t)NB * NPAD * 4) + 1023) & ~(size_t)1023; // u64 [NB*16*16*64]

// ---------------------------------------------------------------------------
// K1: per-anchor score = sigmoid(conf) * max(softmax(cls)), label = argmax.
// NOTE: numerics (lane->class map, sum order) frozen — rank ties depend on it.
// ---------------------------------------------------------------------------
__global__ __launch_bounds__(256) void k_score(const float* __restrict__ conf,
                                               const float* __restrict__ cls,
                                               float* __restrict__ scores,
                                               int* __restrict__ labels) {
#pragma clang fp contract(off)
    int t = blockIdx.x * blockDim.x + threadIdx.x;
    int a = t >> 4;          // anchor index in [0, NB*NM)
    int l = t & 15;
    if (a >= NB * NM) return;
    const float* row = cls + (size_t)a * NC;

    float v[5];
#pragma unroll
    for (int k = 0; k < 5; ++k) v[k] = row[l + 16 * k];

    float bv = v[0];
    int bi = l;
#pragma unroll
    for (int k = 1; k < 5; ++k) {
        int c = l + 16 * k;
        if (v[k] > bv) { bv = v[k]; bi = c; }
    }
#pragma unroll
    for (int m = 1; m < 16; m <<= 1) {
        float ov = __shfl_xor(bv, m, 16);
        int   oi = __shfl_xor(bi, m, 16);
        if (ov > bv || (ov == bv && oi < bi)) { bv = ov; bi = oi; }
    }
    float s = 0.0f;
#pragma unroll
    for (int k = 0; k < 5; ++k) s += expf(v[k] - bv);
#pragma unroll
    for (int m = 1; m < 16; m <<= 1) s += __shfl_xor(s, m, 16);

    if (l == 0) {
        float cf  = conf[a];
        float sig = 1.0f / (1.0f + expf(-cf));
        float inv = 1.0f / s;
        scores[a] = sig * inv;
        labels[a] = bi;
    }
}

// ---------------------------------------------------------------------------
// K2: top-k via threshold-compaction + ALL-PAIRS RANK (no sort, no chains).
// One block (1024 thr) per batch, 5 barriers total.
//   T       : 4096-bin histogram + 2-stage wave suffix-scan (as R2-R7)
//   compact : wave-aggregated ballot compaction of keys >= bin T
//   rank(t) = #{j : key[j] > key[t]}  — C~1005 LDS *broadcast* reads,
//             2 keys per ulonglong2 read; keys unique -> exact lax.top_k.
// Writes out_scores + top_idx only (decode split out for gather MLP).
// ---------------------------------------------------------------------------
__global__ __launch_bounds__(1024) void k_topk(const float* __restrict__ scores,
                                               float* __restrict__ out_scores,
                                               int* __restrict__ top_idx) {
    __shared__ uint32_t hist[NBINS];              // 16 KiB
    __shared__ __align__(16) uint64_t key[NCAND]; // 16 KiB
    __shared__ int sT, scnt;
    int b = blockIdx.x, tid = threadIdx.x;
    const float* sb = scores + (size_t)b * NM;

    for (int i = tid; i < NBINS; i += 1024) hist[i] = 0;
    for (int i = tid; i < NCAND; i += 1024) key[i] = 0;   // zero-pad for all-pairs
    if (tid == 0) scnt = 0;
    __syncthreads();

    // histogram of top-12 float bits (scores > 0 -> bit-monotone)
    for (int i = tid; i < NM; i += 1024)
        atomicAdd(&hist[__float_as_uint(sb[i]) >> 20], 1u);
    __syncthreads();

    // threshold bin T: largest T with count(bin >= T) >= NTOP (2-stage scan)
    if (tid < 64) {
        int l = tid;
        uint32_t q = 0;
        for (int i = 0; i < 64; ++i) q += hist[l * 64 + i];
        uint32_t s = q;
        for (int off = 1; off < 64; off <<= 1) {
            uint32_t o = __shfl_down(s, off);
            if (l + off < 64) s += o;
        }
        uint64_t m = __ballot(s >= (uint32_t)NTOP);
        int c = 63 - __clzll(m);
        uint32_t sc_ = __shfl(s, c);
        uint32_t qc  = __shfl(q, c);
        uint32_t tail = sc_ - qc;
        uint32_t v = hist[c * 64 + l];
        uint32_t s2 = v;
        for (int off = 1; off < 64; off <<= 1) {
            uint32_t o = __shfl_down(s2, off);
            if (l + off < 64) s2 += o;
        }
        uint64_t m2 = __ballot(s2 + tail >= (uint32_t)NTOP);
        int T = c * 64 + (63 - __clzll(m2));
        if (l == 0) sT = T;
    }
    __syncthreads();

    // wave-aggregated compaction of candidates (order irrelevant for rank)
    uint32_t T = (uint32_t)sT;
    int lane = tid & 63;
    for (int i = tid; i < NM; i += 1024) {
        uint32_t bits = __float_as_uint(sb[i]);
        bool pred = (bits >> 20) >= T;
        uint64_t mask = __ballot(pred);
        if (pred) {
            int leader = __ffsll((unsigned long long)mask) - 1;
            int prefix = __popcll(mask & ((1ull << lane) - 1));
            int base = 0;
            if (lane == leader) base = atomicAdd(&scnt, (int)__popcll(mask));
            base = __shfl(base, leader);
            int pos = base + prefix;
            if (pos < NCAND)
                key[pos] = ((uint64_t)bits << 32) | (uint32_t)(~(uint32_t)i);
        }
    }
    __syncthreads();

    // all-pairs rank + scatter (keys unique; zero pads never rank)
    int C = scnt; if (C > NCAND) C = NCAND;
    int C2 = (C + 1) >> 1;
    const ulonglong2* k2 = (const ulonglong2*)key;
    for (int t = tid; t < C; t += 1024) {
        uint64_t kt = key[t];
        uint32_t rank = 0;
        for (int j = 0; j < C2; ++j) {
            ulonglong2 kk = k2[j];                 // broadcast read (uniform j)
            rank += (kk.x > kt) ? 1u : 0u;
            rank += (kk.y > kt) ? 1u : 0u;
        }
        if (rank < (uint32_t)NTOP) {
            out_scores[b * NTOP + rank] = __uint_as_float((uint32_t)(kt >> 32));
            top_idx[b * NPAD + rank]    = (int)(~(uint32_t)kt);
        }
    }
}

// ---------------------------------------------------------------------------
// K3: gather top-1000 labels, decode + normalize + clip boxes.
// Standalone kernel: 125 blocks -> high memory-level parallelism for the
// scattered reg/anchor/label gathers (measured ~2.5 us in R1-R3).
// ---------------------------------------------------------------------------
__global__ __launch_bounds__(256) void k_decode(const int* __restrict__ top_idx,
                                                const int* __restrict__ labels,
                                                const float* __restrict__ reg,
                                                const float* __restrict__ anchors,
                                                const float* __restrict__ stridemap,
                                                float* __restrict__ out_labels,
                                                float* __restrict__ out_boxes,
                                                float* __restrict__ nbox,
                                                int* __restrict__ nlab) {
#pragma clang fp contract(off)
    int t = blockIdx.x * blockDim.x + threadIdx.x;
    if (t >= NB * NTOP) return;
    int b = t / NTOP, r = t % NTOP;
    int idx = top_idx[b * NPAD + r];
    int lab = labels[(size_t)b * NM + idx];
    out_labels[b * NTOP + r] = (float)lab;

    const float* rg = reg + ((size_t)b * NM + idx) * 4;
    float rx = rg[0], ry = rg[1], rw = rg[2], rh = rg[3];
    const float* an = anchors + (size_t)idx * 4;
    float ax = an[0], ay = an[1], aw = an[2], ah = an[3];
    float st = stridemap[idx];

    float sx = 1.0f / (1.0f + expf(-rx));
    float sy = 1.0f / (1.0f + expf(-ry));
    float cx = ax + sx * st;
    float cy = ay + sy * st;
    float w  = aw * expf(rw);
    float h  = ah * expf(rh);
    float x1 = cx - 0.5f * w, y1 = cy - 0.5f * h;
    float x2 = cx + 0.5f * w, y2 = cy + 0.5f * h;

    float nx1 = fminf(fmaxf(x1 / IMGSZ, 0.0f), 1.0f);
    float ny1 = fminf(fmaxf(y1 / IMGSZ, 0.0f), 1.0f);
    float nx2 = fminf(fmaxf(x2 / IMGSZ, 0.0f), 1.0f);
    float ny2 = fminf(fmaxf(y2 / IMGSZ, 0.0f), 1.0f);

    float4 bx = make_float4(nx1, ny1, nx2, ny2);
    ((float4*)out_boxes)[b * NTOP + r] = bx;
    ((float4*)nbox)[b * NPAD + r]      = bx;
    nlab[b * NPAD + r] = lab;
}

// ---------------------------------------------------------------------------
// K4: suppression bit-matrix. 256-thr block per 64x64 tile; 4 waves, each
// wave owns 16 columns. lane = row i (box in regs); column box broadcast
// via __shfl (wave-uniform index); column word = __ballot(pred).
// sup[b][tj][ti][j0]: bit ii set iff i=ti*64+ii suppresses j=tj*64+j0.
// ---------------------------------------------------------------------------
__global__ __launch_bounds__(256) void k_supmat(const float* __restrict__ nbox,
                                                const int* __restrict__ nlab,
                                                uint64_t* __restrict__ sup) {
#pragma clang fp contract(off)
    int b = blockIdx.y;
    int t = blockIdx.x;                 // 0..135 triangular pair index
    int tj = (int)((sqrtf(8.0f * (float)t + 1.0f) - 1.0f) * 0.5f);
    while ((tj + 1) * (tj + 2) / 2 <= t) ++tj;
    while (tj * (tj + 1) / 2 > t) --tj;
    int ti = t - tj * (tj + 1) / 2;

    int lane = threadIdx.x & 63;
    int w    = threadIdx.x >> 6;        // column quarter 0..3

    int i = ti * 64 + lane;             // row owned by this lane
    int j = tj * 64 + lane;             // column data this lane republishes

    float4 bi = ((const float4*)nbox)[b * NPAD + i];
    float  ai = (bi.z - bi.x) * (bi.w - bi.y);
    int    li = nlab[b * NPAD + i];
    float4 bj = ((const float4*)nbox)[b * NPAD + j];
    int    lj = nlab[b * NPAD + j];
    bool   iv = (i < NTOP);

    uint64_t mybits = 0;
#pragma unroll
    for (int u = 0; u < 16; ++u) {
        int jj = (w << 4) | u;          // wave-uniform column index
        float bjx = __shfl(bj.x, jj);
        float bjy = __shfl(bj.y, jj);
        float bjz = __shfl(bj.z, jj);
        float bjw = __shfl(bj.w, jj);
        int   ljv = __shfl(lj, jj);
        float ajv = (bjz - bjx) * (bjw - bjy);
        int   jg  = tj * 64 + jj;
        float xx1 = fmaxf(bi.x, bjx);
        float yy1 = fmaxf(bi.y, bjy);
        float xx2 = fminf(bi.z, bjz);
        float yy2 = fminf(bi.w, bjw);
        float inter = fmaxf(EPSF, xx2 - xx1) * fmaxf(EPSF, yy2 - yy1);
        float uni   = fmaxf(ai + ajv - inter, EPSF);
        float iou   = inter / uni;
        bool pred = (i < jg) && iv && (jg < NTOP) && (li == ljv) && (iou > NMS_TH);
        uint64_t bal = __ballot(pred);
        if (lane == jj) mybits = bal;
    }
    if ((lane >> 4) == w)
        sup[(((size_t)b * 16 + tj) * 16 + ti) * 64 + lane] = mybits;
}

// ---------------------------------------------------------------------------
// K5: greedy NMS scan, 16 waves per batch (wave w = column-block tj=w).
// ---------------------------------------------------------------------------
__global__ __launch_bounds__(1024) void k_nms(const float* __restrict__ out_scores,
                                              const uint64_t* __restrict__ sup,
                                              float* __restrict__ out_keep) {
    __shared__ uint64_t Kw[16];
    int b    = blockIdx.x;
    int w    = threadIdx.x >> 6;    // wave id = tj block
    int lane = threadIdx.x & 63;
    const uint64_t* supb = sup + (size_t)b * 16 * 16 * 64;

    uint64_t wrow[16];
#pragma unroll
    for (int ti = 0; ti < 16; ++ti)
        wrow[ti] = (ti <= w) ? supb[((size_t)w * 16 + ti) * 64 + lane] : 0ULL;

    int pos = w * 64 + lane;
    bool k0 = (pos < NTOP) && (out_scores[b * NTOP + pos] >= CONF_TH);

    uint64_t ext = 0;
#pragma unroll
    for (int s = 0; s < 16; ++s) {
        if (w == s) {
            bool cand = k0 && (ext == 0ULL);
            uint64_t wself = wrow[s];
            uint64_t alive = __ballot(cand);
            for (int it = 0; it < 64; ++it) {
                bool dead = (wself & alive) != 0ULL;
                uint64_t na = __ballot(cand && !dead);
                if (na == alive) break;
                alive = na;
            }
            if (lane == 0) Kw[s] = alive;
            if (pos < NTOP)
                out_keep[b * NTOP + pos] = ((alive >> lane) & 1ULL) ? 1.0f : 0.0f;
        }
        __syncthreads();
        if (w > s) ext |= wrow[s] & Kw[s];
    }
}

// ---------------------------------------------------------------------------
extern "C" void kernel_launch(void* const* d_in, const int* in_sizes, int n_in,
                              void* d_out, int out_size, void* d_ws, size_t ws_size,
                              hipStream_t stream) {
    const float* conf = (const float*)d_in[0];
    const float* cls  = (const float*)d_in[1];
    const float* reg  = (const float*)d_in[2];
    const float* anch = (const float*)d_in[3];
    const float* strm = (const float*)d_in[4];

    float* out        = (float*)d_out;
    float* out_scores = out;
    float* out_labels = out + NB * NTOP;
    float* out_boxes  = out + 2 * NB * NTOP;
    float* out_keep   = out + 2 * NB * NTOP + NB * NTOP * 4;

    char* ws = (char*)d_ws;
    float*    scores = (float*)(ws + OFF_SCORES);
    int*      labels = (int*)(ws + OFF_LABELS);
    int*      tidx   = (int*)(ws + OFF_TIDX);
    float*    nbox   = (float*)(ws + OFF_NBOX);
    int*      nlab   = (int*)(ws + OFF_NLAB);
    uint64_t* sup    = (uint64_t*)(ws + OFF_SUP);

    k_score<<<(NB * NM * 16) / 256, 256, 0, stream>>>(conf, cls, scores, labels);
    k_topk<<<NB, 1024, 0, stream>>>(scores, out_scores, tidx);
    k_decode<<<(NB * NTOP + 255) / 256, 256, 0, stream>>>(tidx, labels, reg, anch, strm,
                                                          out_labels, out_boxes, nbox, nlab);
    k_supmat<<<dim3(136, NB), 256, 0, stream>>>(nbox, nlab, sup);
    k_nms<<<NB, 1024, 0, stream>>>(out_scores, sup, out_keep);
}

// Round 10
// 79.292 us; speedup vs baseline: 1.6764x; 1.0131x over previous
//
#include <hip/hip_runtime.h>
#include <stdint.h>

#define NB 32
#define NM 6300
#define NC 80
#define NTOP 1000
#define NPAD 1024
#define NCAND 2048
#define NBINS 4096

static constexpr float IMGSZ   = 320.0f;
static constexpr float CONF_TH = 0.05f;
static constexpr float NMS_TH  = 0.6f;
static constexpr float EPSF    = 1e-10f;

// ---- workspace layout (bytes) ----
static constexpr size_t OFF_SCORES = 0;                                    // f32 [NB*NM]
static constexpr size_t OFF_LABELS = OFF_SCORES + (size_t)NB * NM * 4;     // i32 [NB*NM]
static constexpr size_t OFF_TIDX   = OFF_LABELS + (size_t)NB * NM * 4;     // i32 [NB*NPAD]
static constexpr size_t OFF_NBOX   = OFF_TIDX   + (size_t)NB * NPAD * 4;   // f32 [NB*NPAD*4]
static constexpr size_t OFF_NLAB   = OFF_NBOX   + (size_t)NB * NPAD * 16;  // i32 [NB*NPAD]
static constexpr size_t OFF_SUP    = ((OFF_NLAB + (size_t)NB * NPAD * 4) + 1023) & ~(size_t)1023; // u64 [NB*16*16*64]

// ---------------------------------------------------------------------------
// K1: per-anchor score = sigmoid(conf) * max(softmax(cls)), label = argmax.
// NOTE: numerics (lane->class map, sum order) frozen — rank ties depend on it.
// ---------------------------------------------------------------------------
__global__ __launch_bounds__(256) void k_score(const float* __restrict__ conf,
                                               const float* __restrict__ cls,
                                               float* __restrict__ scores,
                                               int* __restrict__ labels) {
#pragma clang fp contract(off)
    int t = blockIdx.x * blockDim.x + threadIdx.x;
    int a = t >> 4;          // anchor index in [0, NB*NM)
    int l = t & 15;
    if (a >= NB * NM) return;
    const float* row = cls + (size_t)a * NC;

    float v[5];
#pragma unroll
    for (int k = 0; k < 5; ++k) v[k] = row[l + 16 * k];

    float bv = v[0];
    int bi = l;
#pragma unroll
    for (int k = 1; k < 5; ++k) {
        int c = l + 16 * k;
        if (v[k] > bv) { bv = v[k]; bi = c; }
    }
#pragma unroll
    for (int m = 1; m < 16; m <<= 1) {
        float ov = __shfl_xor(bv, m, 16);
        int   oi = __shfl_xor(bi, m, 16);
        if (ov > bv || (ov == bv && oi < bi)) { bv = ov; bi = oi; }
    }
    float s = 0.0f;
#pragma unroll
    for (int k = 0; k < 5; ++k) s += expf(v[k] - bv);
#pragma unroll
    for (int m = 1; m < 16; m <<= 1) s += __shfl_xor(s, m, 16);

    if (l == 0) {
        float cf  = conf[a];
        float sig = 1.0f / (1.0f + expf(-cf));
        float inv = 1.0f / s;
        scores[a] = sig * inv;
        labels[a] = bi;
    }
}

// ---------------------------------------------------------------------------
// K2: top-k via threshold-compaction + all-pairs rank.
// R10 changes vs R9 (MLP fixes, same algorithm):
//  - rank loop: 4 independent ulonglong2 loads in flight (was 1 serial
//    broadcast read -> full 120cy LDS latency per iteration)
//  - chunk-sum scan: rotated index kills the 32-way bank conflict
// Keys (score_bits<<32 | ~idx) unique -> exact lax.top_k order.
// ---------------------------------------------------------------------------
__global__ __launch_bounds__(1024) void k_topk(const float* __restrict__ scores,
                                               float* __restrict__ out_scores,
                                               int* __restrict__ top_idx) {
    __shared__ uint32_t hist[NBINS];              // 16 KiB
    __shared__ __align__(16) uint64_t key[NCAND]; // 16 KiB
    __shared__ int sT, scnt;
    int b = blockIdx.x, tid = threadIdx.x;
    const float* sb = scores + (size_t)b * NM;

    for (int i = tid; i < NBINS; i += 1024) hist[i] = 0;
    for (int i = tid; i < NCAND; i += 1024) key[i] = 0;   // zero-pad for all-pairs
    if (tid == 0) scnt = 0;
    __syncthreads();

    // histogram of top-12 float bits (scores > 0 -> bit-monotone)
    for (int i = tid; i < NM; i += 1024)
        atomicAdd(&hist[__float_as_uint(sb[i]) >> 20], 1u);
    __syncthreads();

    // threshold bin T: largest T with count(bin >= T) >= NTOP (2-stage scan)
    if (tid < 64) {
        int l = tid;
        uint32_t q = 0;
        // rotated read: bank = (k + l) % 32 -> 2 lanes/bank (free), exact sum
        for (int k = 0; k < 64; ++k) q += hist[l * 64 + ((k + l) & 63)];
        uint32_t s = q;
        for (int off = 1; off < 64; off <<= 1) {
            uint32_t o = __shfl_down(s, off);
            if (l + off < 64) s += o;
        }
        uint64_t m = __ballot(s >= (uint32_t)NTOP);
        int c = 63 - __clzll(m);
        uint32_t sc_ = __shfl(s, c);
        uint32_t qc  = __shfl(q, c);
        uint32_t tail = sc_ - qc;
        uint32_t v = hist[c * 64 + l];
        uint32_t s2 = v;
        for (int off = 1; off < 64; off <<= 1) {
            uint32_t o = __shfl_down(s2, off);
            if (l + off < 64) s2 += o;
        }
        uint64_t m2 = __ballot(s2 + tail >= (uint32_t)NTOP);
        int T = c * 64 + (63 - __clzll(m2));
        if (l == 0) sT = T;
    }
    __syncthreads();

    // wave-aggregated compaction of candidates (order irrelevant for rank)
    uint32_t T = (uint32_t)sT;
    int lane = tid & 63;
    for (int i = tid; i < NM; i += 1024) {
        uint32_t bits = __float_as_uint(sb[i]);
        bool pred = (bits >> 20) >= T;
        uint64_t mask = __ballot(pred);
        if (pred) {
            int leader = __ffsll((unsigned long long)mask) - 1;
            int prefix = __popcll(mask & ((1ull << lane) - 1));
            int base = 0;
            if (lane == leader) base = atomicAdd(&scnt, (int)__popcll(mask));
            base = __shfl(base, leader);
            int pos = base + prefix;
            if (pos < NCAND)
                key[pos] = ((uint64_t)bits << 32) | (uint32_t)(~(uint32_t)i);
        }
    }
    __syncthreads();

    // all-pairs rank + scatter; 4 independent 16B loads in flight per step.
    // Pads are 0 and never out-rank a real key; keys unique -> ranks unique.
    int C = scnt; if (C > NCAND) C = NCAND;
    int C2 = (C + 1) >> 1;               // ulonglong2 entries holding real keys
    int jmax = (C2 + 3) & ~3;            // multiple of 4; k2 valid to 1024
    const ulonglong2* k2 = (const ulonglong2*)key;
    for (int t = tid; t < C; t += 1024) {
        uint64_t kt = key[t];
        uint32_t rank = 0;
        for (int j = 0; j < jmax; j += 4) {
            ulonglong2 a0 = k2[j + 0];
            ulonglong2 a1 = k2[j + 1];
            ulonglong2 a2 = k2[j + 2];
            ulonglong2 a3 = k2[j + 3];
            rank += (a0.x > kt) ? 1u : 0u;
            rank += (a0.y > kt) ? 1u : 0u;
            rank += (a1.x > kt) ? 1u : 0u;
            rank += (a1.y > kt) ? 1u : 0u;
            rank += (a2.x > kt) ? 1u : 0u;
            rank += (a2.y > kt) ? 1u : 0u;
            rank += (a3.x > kt) ? 1u : 0u;
            rank += (a3.y > kt) ? 1u : 0u;
        }
        if (rank < (uint32_t)NTOP) {
            out_scores[b * NTOP + rank] = __uint_as_float((uint32_t)(kt >> 32));
            top_idx[b * NPAD + rank]    = (int)(~(uint32_t)kt);
        }
    }
}

// ---------------------------------------------------------------------------
// K3: gather top-1000 labels, decode + normalize + clip boxes.
// Standalone kernel: 125 blocks -> high memory-level parallelism.
// ---------------------------------------------------------------------------
__global__ __launch_bounds__(256) void k_decode(const int* __restrict__ top_idx,
                                                const int* __restrict__ labels,
                                                const float* __restrict__ reg,
                                                const float* __restrict__ anchors,
                                                const float* __restrict__ stridemap,
                                                float* __restrict__ out_labels,
                                                float* __restrict__ out_boxes,
                                                float* __restrict__ nbox,
                                                int* __restrict__ nlab) {
#pragma clang fp contract(off)
    int t = blockIdx.x * blockDim.x + threadIdx.x;
    if (t >= NB * NTOP) return;
    int b = t / NTOP, r = t % NTOP;
    int idx = top_idx[b * NPAD + r];
    int lab = labels[(size_t)b * NM + idx];
    out_labels[b * NTOP + r] = (float)lab;

    const float* rg = reg + ((size_t)b * NM + idx) * 4;
    float rx = rg[0], ry = rg[1], rw = rg[2], rh = rg[3];
    const float* an = anchors + (size_t)idx * 4;
    float ax = an[0], ay = an[1], aw = an[2], ah = an[3];
    float st = stridemap[idx];

    float sx = 1.0f / (1.0f + expf(-rx));
    float sy = 1.0f / (1.0f + expf(-ry));
    float cx = ax + sx * st;
    float cy = ay + sy * st;
    float w  = aw * expf(rw);
    float h  = ah * expf(rh);
    float x1 = cx - 0.5f * w, y1 = cy - 0.5f * h;
    float x2 = cx + 0.5f * w, y2 = cy + 0.5f * h;

    float nx1 = fminf(fmaxf(x1 / IMGSZ, 0.0f), 1.0f);
    float ny1 = fminf(fmaxf(y1 / IMGSZ, 0.0f), 1.0f);
    float nx2 = fminf(fmaxf(x2 / IMGSZ, 0.0f), 1.0f);
    float ny2 = fminf(fmaxf(y2 / IMGSZ, 0.0f), 1.0f);

    float4 bx = make_float4(nx1, ny1, nx2, ny2);
    ((float4*)out_boxes)[b * NTOP + r] = bx;
    ((float4*)nbox)[b * NPAD + r]      = bx;
    nlab[b * NPAD + r] = lab;
}

// ---------------------------------------------------------------------------
// K4: suppression bit-matrix. 256-thr block per 64x64 tile; 4 waves, each
// wave owns 16 columns. lane = row i (box in regs); column box broadcast
// via __shfl (wave-uniform index); column word = __ballot(pred).
// sup[b][tj][ti][j0]: bit ii set iff i=ti*64+ii suppresses j=tj*64+j0.
// ---------------------------------------------------------------------------
__global__ __launch_bounds__(256) void k_supmat(const float* __restrict__ nbox,
                                                const int* __restrict__ nlab,
                                                uint64_t* __restrict__ sup) {
#pragma clang fp contract(off)
    int b = blockIdx.y;
    int t = blockIdx.x;                 // 0..135 triangular pair index
    int tj = (int)((sqrtf(8.0f * (float)t + 1.0f) - 1.0f) * 0.5f);
    while ((tj + 1) * (tj + 2) / 2 <= t) ++tj;
    while (tj * (tj + 1) / 2 > t) --tj;
    int ti = t - tj * (tj + 1) / 2;

    int lane = threadIdx.x & 63;
    int w    = threadIdx.x >> 6;        // column quarter 0..3

    int i = ti * 64 + lane;             // row owned by this lane
    int j = tj * 64 + lane;             // column data this lane republishes

    float4 bi = ((const float4*)nbox)[b * NPAD + i];
    float  ai = (bi.z - bi.x) * (bi.w - bi.y);
    int    li = nlab[b * NPAD + i];
    float4 bj = ((const float4*)nbox)[b * NPAD + j];
    int    lj = nlab[b * NPAD + j];
    bool   iv = (i < NTOP);

    uint64_t mybits = 0;
#pragma unroll
    for (int u = 0; u < 16; ++u) {
        int jj = (w << 4) | u;          // wave-uniform column index
        float bjx = __shfl(bj.x, jj);
        float bjy = __shfl(bj.y, jj);
        float bjz = __shfl(bj.z, jj);
        float bjw = __shfl(bj.w, jj);
        int   ljv = __shfl(lj, jj);
        float ajv = (bjz - bjx) * (bjw - bjy);
        int   jg  = tj * 64 + jj;
        float xx1 = fmaxf(bi.x, bjx);
        float yy1 = fmaxf(bi.y, bjy);
        float xx2 = fminf(bi.z, bjz);
        float yy2 = fminf(bi.w, bjw);
        float inter = fmaxf(EPSF, xx2 - xx1) * fmaxf(EPSF, yy2 - yy1);
        float uni   = fmaxf(ai + ajv - inter, EPSF);
        float iou   = inter / uni;
        bool pred = (i < jg) && iv && (jg < NTOP) && (li == ljv) && (iou > NMS_TH);
        uint64_t bal = __ballot(pred);
        if (lane == jj) mybits = bal;
    }
    if ((lane >> 4) == w)
        sup[(((size_t)b * 16 + tj) * 16 + ti) * 64 + lane] = mybits;
}

// ---------------------------------------------------------------------------
// K5: greedy NMS scan, 16 waves per batch (wave w = column-block tj=w).
// ---------------------------------------------------------------------------
__global__ __launch_bounds__(1024) void k_nms(const float* __restrict__ out_scores,
                                              const uint64_t* __restrict__ sup,
                                              float* __restrict__ out_keep) {
    __shared__ uint64_t Kw[16];
    int b    = blockIdx.x;
    int w    = threadIdx.x >> 6;    // wave id = tj block
    int lane = threadIdx.x & 63;
    const uint64_t* supb = sup + (size_t)b * 16 * 16 * 64;

    uint64_t wrow[16];
#pragma unroll
    for (int ti = 0; ti < 16; ++ti)
        wrow[ti] = (ti <= w) ? supb[((size_t)w * 16 + ti) * 64 + lane] : 0ULL;

    int pos = w * 64 + lane;
    bool k0 = (pos < NTOP) && (out_scores[b * NTOP + pos] >= CONF_TH);

    uint64_t ext = 0;
#pragma unroll
    for (int s = 0; s < 16; ++s) {
        if (w == s) {
            bool cand = k0 && (ext == 0ULL);
            uint64_t wself = wrow[s];
            uint64_t alive = __ballot(cand);
            for (int it = 0; it < 64; ++it) {
                bool dead = (wself & alive) != 0ULL;
                uint64_t na = __ballot(cand && !dead);
                if (na == alive) break;
                alive = na;
            }
            if (lane == 0) Kw[s] = alive;
            if (pos < NTOP)
                out_keep[b * NTOP + pos] = ((alive >> lane) & 1ULL) ? 1.0f : 0.0f;
        }
        __syncthreads();
        if (w > s) ext |= wrow[s] & Kw[s];
    }
}

// ---------------------------------------------------------------------------
extern "C" void kernel_launch(void* const* d_in, const int* in_sizes, int n_in,
                              void* d_out, int out_size, void* d_ws, size_t ws_size,
                              hipStream_t stream) {
    const float* conf = (const float*)d_in[0];
    const float* cls  = (const float*)d_in[1];
    const float* reg  = (const float*)d_in[2];
    const float* anch = (const float*)d_in[3];
    const float* strm = (const float*)d_in[4];

    float* out        = (float*)d_out;
    float* out_scores = out;
    float* out_labels = out + NB * NTOP;
    float* out_boxes  = out + 2 * NB * NTOP;
    float* out_keep   = out + 2 * NB * NTOP + NB * NTOP * 4;

    char* ws = (char*)d_ws;
    float*    scores = (float*)(ws + OFF_SCORES);
    int*      labels = (int*)(ws + OFF_LABELS);
    int*      tidx   = (int*)(ws + OFF_TIDX);
    float*    nbox   = (float*)(ws + OFF_NBOX);
    int*      nlab   = (int*)(ws + OFF_NLAB);
    uint64_t* sup    = (uint64_t*)(ws + OFF_SUP);

    k_score<<<(NB * NM * 16) / 256, 256, 0, stream>>>(conf, cls, scores, labels);
    k_topk<<<NB, 1024, 0, stream>>>(scores, out_scores, tidx);
    k_decode<<<(NB * NTOP + 255) / 256, 256, 0, stream>>>(tidx, labels, reg, anch, strm,
                                                          out_labels, out_boxes, nbox, nlab);
    k_supmat<<<dim3(136, NB), 256, 0, stream>>>(nbox, nlab, sup);
    k_nms<<<NB, 1024, 0, stream>>>(out_scores, sup, out_keep);
}